// Round 8
// baseline (334.308 us; speedup 1.0000x reference)
//
#include <hip/hip_runtime.h>

#define NUM_NODES 50000
#define WINDOW 8
#define DIM 256
#define BATCH 8192
#define NROWS (NUM_NODES * WINDOW)          // 400000 rows
#define ROW4  (DIM / 4)                     // 64 float4 per row
#define BANK4 ((long)NROWS * ROW4)          // 25.6M float4
#define TS4   (NROWS / 4)                   // 100K float4

typedef float f4 __attribute__((ext_vector_type(4)));

// ---- N1: pure streaming copy (m13 pattern, no data dependencies) --------------------
// bank: 409.6 MB r + 409.6 MB w. ts: 1.6 MB r+w. ptr prefill: out_ptr = float(ptr).
__global__ void __launch_bounds__(256)
copy_kernel(const f4* __restrict__ bank4, const f4* __restrict__ ts4,
            const int* __restrict__ ptr,
            f4* __restrict__ out_bank4, f4* __restrict__ out_ts4,
            float* __restrict__ out_ptr) {
    const long tid = (long)blockIdx.x * 256 + threadIdx.x;
    const long nth = (long)gridDim.x * 256;          // 524288 threads
    for (long i = tid; i < BANK4; i += nth)
        out_bank4[i] = bank4[i];
    if (tid < TS4) out_ts4[tid] = ts4[tid];
    if (tid < NUM_NODES) out_ptr[tid] = (float)ptr[tid];
}

// ---- N2: count+rank via LDS broadcast scan, then scatter winners over the copy ------
// 32 blocks x 256 threads = 8192 (one per batch element). All threads of a block scan
// the same LDS entry per iteration -> broadcast, conflict-free (~8192 iters, ~10us).
//   c    = total occurrences of my node in the batch
//   rank = occurrences before me  (== torch sequential-write order)
// Winner iff rank >= c-8 (last writer per slot); winners of one node have distinct
// slots -> every output cell has exactly one writer -> deterministic, order-free.
// rank==c-1 element (unique per touched node) writes ptr_new = ptr + c.
__global__ void __launch_bounds__(256)
finalize_kernel(const int* __restrict__ idx, const int* __restrict__ ptr,
                const f4* __restrict__ nrep4, const float* __restrict__ t,
                f4* __restrict__ out_bank4, float* __restrict__ out_ts,
                float* __restrict__ out_ptr) {
    __shared__ int sidx[BATCH];        // 32 KiB
    __shared__ int srow[256];          // dest row of this block's winners (-1 = none)
    const int tid = threadIdx.x;
    const int bi  = blockIdx.x * 256 + tid;

    for (int j = tid; j < BATCH; j += 256) sidx[j] = idx[j];
    __syncthreads();

    const int node = sidx[bi];
    int c = 0, rank = 0;
    for (int m = 0; m < BATCH; ++m) {
        int e = (sidx[m] == node) ? 1 : 0;
        c += e;
        rank += (m < bi) ? e : 0;
    }

    int row = -1;
    if (rank >= c - WINDOW)
        row = node * WINDOW + ((ptr[node] + rank) & (WINDOW - 1));   // ptr >= 0
    srow[tid] = row;

    if (rank == c - 1) out_ptr[node] = (float)(ptr[node] + c);       // exact in f32
    if (row >= 0)      out_ts[row]   = t[bi];
    __syncthreads();

    // wave-parallel scatter: one row (64 lanes x float4) per wave-iteration, coalesced
    const int wave = tid >> 6, lane = tid & 63;
    for (int e = wave; e < 256; e += 4) {
        int r = srow[e];
        if (r < 0) continue;
        long b = (long)(blockIdx.x * 256 + e);
        out_bank4[(long)r * ROW4 + lane] = nrep4[b * ROW4 + lane];
    }
}

extern "C" void kernel_launch(void* const* d_in, const int* in_sizes, int n_in,
                              void* d_out, int out_size, void* d_ws, size_t ws_size,
                              hipStream_t stream) {
    const float* bank       = (const float*)d_in[0];
    const float* timestamps = (const float*)d_in[1];
    const float* nrep       = (const float*)d_in[2];
    const float* t          = (const float*)d_in[3];
    const int*   ptr        = (const int*)  d_in[4];
    const int*   idx        = (const int*)  d_in[5];

    float* out_bank = (float*)d_out;
    float* out_ts   = out_bank + (size_t)NUM_NODES * WINDOW * DIM;
    float* out_ptr  = out_ts   + (size_t)NUM_NODES * WINDOW;

    copy_kernel<<<2048, 256, 0, stream>>>(
        (const f4*)bank, (const f4*)timestamps, ptr,
        (f4*)out_bank, (f4*)out_ts, out_ptr);

    finalize_kernel<<<BATCH / 256, 256, 0, stream>>>(
        idx, ptr, (const f4*)nrep, t,
        (f4*)out_bank, out_ts, out_ptr);
}

// Round 9
// 280.150 us; speedup vs baseline: 1.1933x; 1.1933x over previous
//
#include <hip/hip_runtime.h>

#define NUM_NODES 50000
#define WINDOW 8
#define DIM 256
#define BATCH 8192
#define NROWS (NUM_NODES * WINDOW)          // 400000 rows
#define ROW4  (DIM / 4)                     // 64 float4 per row
#define BANK4 ((long)NROWS * ROW4)          // 25.6M float4

// ws layout (ints): count[50000] | dupN[1] | duplist[8192] | winner[400000]

// ---- K1: per-node occurrence count (order-independent atomics) ----------------------
__global__ void __launch_bounds__(256)
count_kernel(const int* __restrict__ idx, int* __restrict__ count) {
    int bi = blockIdx.x * 256 + threadIdx.x;
    if (bi < BATCH) atomicAdd(&count[idx[bi]], 1);
}

// ---- K2: classify (c==1 -> direct winner) + ptr_new fused ---------------------------
// count==1 => rank 0, always a winner. count>1 => append to duplist (order
// irrelevant: K3 ranks by batch position => deterministic).
__global__ void __launch_bounds__(256)
classify_kernel(const int* __restrict__ idx, const int* __restrict__ ptr,
                const int* __restrict__ count, int* __restrict__ winner,
                int* __restrict__ duplist, int* __restrict__ dupN,
                float* __restrict__ out_ptr) {
    int i = blockIdx.x * 256 + threadIdx.x;          // grid covers 50176
    if (i < NUM_NODES) out_ptr[i] = (float)(ptr[i] + count[i]);   // exact in f32
    if (i < BATCH) {
        int node = idx[i];
        if (count[node] == 1)
            winner[node * WINDOW + (ptr[node] & (WINDOW - 1))] = i;
        else
            duplist[atomicAdd(dupN, 1)] = i;
    }
}

// ---- K3: rank duplicates — LDS-staged O(n^2/8192), n ~ 1.3K (max 8192) --------------
// rank over dup list == full batch rank (all occurrences of a dup node are listed).
// Winner iff rank >= c-8 (last writer per slot); winners of one node get distinct
// slots -> unique writer per (node,slot) cell.
__global__ void __launch_bounds__(256)
dup_rank_kernel(const int* __restrict__ idx, const int* __restrict__ ptr,
                const int* __restrict__ count,
                const int* __restrict__ duplist, const int* __restrict__ dupN,
                int* __restrict__ winner) {
    __shared__ int spos [BATCH];           // 32 KiB
    __shared__ int snode[BATCH];           // 32 KiB
    int n = *dupN;
    for (int k = threadIdx.x; k < n; k += 256) {
        int p = duplist[k];
        spos [k] = p;
        snode[k] = idx[p];
    }
    __syncthreads();

    int k = blockIdx.x * 256 + threadIdx.x;
    if (k >= n) return;
    int p    = spos[k];
    int node = snode[k];
    int rank = 0;
    for (int m = 0; m < n; ++m)
        rank += (spos[m] < p && snode[m] == node);

    if (rank >= count[node] - WINDOW)
        winner[node * WINDOW + ((ptr[node] + rank) & (WINDOW - 1))] = p;
}

// ---- K4: fused copy + winner-select (R2's proven hot pass, unchanged) ---------------
__global__ void __launch_bounds__(256)
fused_copy_kernel(const float4* __restrict__ bank4,
                  const float*  __restrict__ ts,
                  const float4* __restrict__ nrep4,
                  const float*  __restrict__ t,
                  const int*    __restrict__ winner,
                  float4* __restrict__ out_bank4,
                  float*  __restrict__ out_ts) {
    const long nth = (long)gridDim.x * 256;
    for (long i = (long)blockIdx.x * 256 + threadIdx.x; i < BANK4; i += nth) {
        int  row = (int)(i >> 6);          // 64 float4s per row
        int  w   = winner[row];
        float4 v = (w >= 0) ? nrep4[(long)w * ROW4 + (i & 63)] : bank4[i];
        out_bank4[i] = v;
        if ((i & 63) == 0)
            out_ts[row] = (w >= 0) ? t[w] : ts[row];
    }
}

extern "C" void kernel_launch(void* const* d_in, const int* in_sizes, int n_in,
                              void* d_out, int out_size, void* d_ws, size_t ws_size,
                              hipStream_t stream) {
    const float* bank       = (const float*)d_in[0];
    const float* timestamps = (const float*)d_in[1];
    const float* nrep       = (const float*)d_in[2];
    const float* t          = (const float*)d_in[3];
    const int*   ptr        = (const int*)  d_in[4];
    const int*   idx        = (const int*)  d_in[5];

    float* out_bank = (float*)d_out;
    float* out_ts   = out_bank + (size_t)NUM_NODES * WINDOW * DIM;
    float* out_ptr  = out_ts   + (size_t)NUM_NODES * WINDOW;

    int* count   = (int*)d_ws;
    int* dupN    = count + NUM_NODES;
    int* duplist = dupN + 1;
    int* winner  = duplist + BATCH;

    // re-init every call (ws persists across replays)
    hipMemsetAsync(count, 0, (NUM_NODES + 1) * sizeof(int), stream);      // count+dupN
    hipMemsetAsync(winner, 0xFF, (size_t)NROWS * sizeof(int), stream);    // winner=-1

    count_kernel   <<<(BATCH + 255) / 256, 256, 0, stream>>>(idx, count);
    classify_kernel<<<(NUM_NODES + 255) / 256, 256, 0, stream>>>(idx, ptr, count,
                                                winner, duplist, dupN, out_ptr);
    dup_rank_kernel<<<(BATCH + 255) / 256, 256, 0, stream>>>(idx, ptr, count,
                                                duplist, dupN, winner);

    fused_copy_kernel<<<2048, 256, 0, stream>>>(
        (const float4*)bank, timestamps, (const float4*)nrep, t, winner,
        (float4*)out_bank, out_ts);
}